// Round 1
// baseline (369.934 us; speedup 1.0000x reference)
//
#include <hip/hip_runtime.h>

// SparseCodebook: out[b] = min_k mean_d |codes[b,d] - centroids[cls[b],k,d]|
// B=262144, NUM_CLASSES=1000, K=4, D=256.
//
// R4: centroids fp32->fp16 in d_ws (2 MB table, L2-resident; gather bytes
// halve to 512 MB). absmax 1.95e-3 vs threshold 7.27e-3.
// R5 theory: kernel is ~2x above its ~45 us roofline from VMEM transaction
// splitting, not bytes. Old layout (4 samples/wave, 1 per quarter) made every
// codes load touch 4 separate 256 B segments and every gather touch 4 random
// class blocks (4 scattered lines/instr). New layout: whole wave owns one
// sample (lane l -> dims [4l,4l+4)):
//   - codes: ONE coalesced 1 KiB load per sample (nontemporal, keep L2 for table)
//   - gathers: 512 B contiguous per instr from a single class block
//   - SPW=8 samples/wave, cls prefetched, codes pipelined 1 ahead (hides the
//     cls->gather serial chain)
//   - k-interleaved butterfly reduce: 9 shuffles/sample instead of 26
// Predict: main kernel ~50-60 us, total 363 -> ~320-335 us.

#define B_TOTAL     262144
#define NUM_CLASSES 1000
#define KC          4
#define DIM         256
#define SPW         8   // samples per wave

typedef float    vf4 __attribute__((ext_vector_type(4)));
typedef _Float16 vh4 __attribute__((ext_vector_type(4)));

// centroids fp32 -> fp16 into ws. 1000*4*256 = 1,024,000 elems = 256,000 vf4.
__global__ __launch_bounds__(256) void convert_kernel(
    const float* __restrict__ cent_f32, _Float16* __restrict__ cent_f16)
{
    const int i = blockIdx.x * 256 + threadIdx.x;           // vf4 index
    const int n = NUM_CLASSES * KC * DIM / 4;               // 256,000
    if (i < n) {
        const vf4 v = ((const vf4*)cent_f32)[i];
        vh4 h;
        h.x = (_Float16)v.x; h.y = (_Float16)v.y;
        h.z = (_Float16)v.z; h.w = (_Float16)v.w;
        ((vh4*)cent_f16)[i] = h;
    }
}

// One sample per wave; lane l covers dims [4l, 4l+4). SPW samples per wave,
// processed sequentially with a 1-deep codes pipeline.
__global__ __launch_bounds__(256) void sparse_codebook_w(
    const float*    __restrict__ codes,
    const int*      __restrict__ pred_class,
    const _Float16* __restrict__ cent_f16,
    float*          __restrict__ out)
{
    const int wave = (blockIdx.x * 256 + threadIdx.x) >> 6;
    const int lane = threadIdx.x & 63;
    const int s0   = wave * SPW;
    if (s0 >= B_TOTAL) return;

    // Prefetch all SPW class ids (broadcast loads; removes cls latency from
    // the per-sample critical path after the first sample).
    int cls[SPW];
#pragma unroll
    for (int s = 0; s < SPW; ++s)
        cls[s] = pred_class[s0 + s];

    const vf4* cv = (const vf4*)codes;

    // Pipeline: codes row for sample s+1 is in flight while computing s.
    vf4 c_next = __builtin_nontemporal_load(&cv[(size_t)s0 * 64 + lane]);

#pragma unroll
    for (int s = 0; s < SPW; ++s) {
        const vf4 c = c_next;
        if (s + 1 < SPW)
            c_next = __builtin_nontemporal_load(
                &cv[(size_t)(s0 + s + 1) * 64 + lane]);

        // Class block: KC rows x 64 vh4. Per-k load = 64 consecutive vh4
        // = 512 B contiguous (one class block, 4 cache lines).
        const vh4* cb = (const vh4*)cent_f16
                      + (size_t)cls[s] * (KC * DIM / 4) + lane;
        const vh4 g0 = cb[0];
        const vh4 g1 = cb[64];
        const vh4 g2 = cb[128];
        const vh4 g3 = cb[192];

        float d0 = fabsf(c.x - (float)g0.x) + fabsf(c.y - (float)g0.y)
                 + fabsf(c.z - (float)g0.z) + fabsf(c.w - (float)g0.w);
        float d1 = fabsf(c.x - (float)g1.x) + fabsf(c.y - (float)g1.y)
                 + fabsf(c.z - (float)g1.z) + fabsf(c.w - (float)g1.w);
        float d2 = fabsf(c.x - (float)g2.x) + fabsf(c.y - (float)g2.y)
                 + fabsf(c.z - (float)g2.z) + fabsf(c.w - (float)g2.w);
        float d3 = fabsf(c.x - (float)g3.x) + fabsf(c.y - (float)g3.y)
                 + fabsf(c.z - (float)g3.z) + fabsf(c.w - (float)g3.w);

        // k-interleaved butterfly: after 3 exchange levels, lane holds the
        // 4-lane partial sum of k = lane&3; 4 more xor levels finish the
        // 64-lane sum; 2 shuffled mins collapse over k. 9 shuffles total.
        const bool b0 = (lane & 1) != 0;
        const bool b1 = (lane & 2) != 0;
        float ka = b0 ? d1 : d0;
        float kb = b0 ? d0 : d1;
        ka += __shfl_xor(kb, 1, 64);
        float kc = b0 ? d3 : d2;
        float kd = b0 ? d2 : d3;
        kc += __shfl_xor(kd, 1, 64);
        float ke = b1 ? kc : ka;
        float kf = b1 ? ka : kc;
        ke += __shfl_xor(kf, 2, 64);
        ke += __shfl_xor(ke, 4, 64);
        ke += __shfl_xor(ke, 8, 64);
        ke += __shfl_xor(ke, 16, 64);
        ke += __shfl_xor(ke, 32, 64);
        // ke = full sum for k = lane&3, replicated across each 4-lane group
        float m = fminf(ke, __shfl_xor(ke, 1, 64));
        m = fminf(m, __shfl_xor(m, 2, 64));

        if (lane == 0)
            __builtin_nontemporal_store(m * (1.0f / (float)DIM),
                                        &out[s0 + s]);
    }
}

extern "C" void kernel_launch(void* const* d_in, const int* in_sizes, int n_in,
                              void* d_out, int out_size, void* d_ws, size_t ws_size,
                              hipStream_t stream) {
    const float* codes = (const float*)d_in[0];
    const int*   pred  = (const int*)d_in[1];
    const float* cents = (const float*)d_in[2];
    float*       out   = (float*)d_out;
    _Float16*    tab   = (_Float16*)d_ws;   // 2 MB fp16 centroid table

    const int nvec = NUM_CLASSES * KC * DIM / 4;  // 256,000
    convert_kernel<<<(nvec + 255) / 256, 256, 0, stream>>>(cents, tab);

    const int waves  = B_TOTAL / SPW;             // 32768
    const int blocks = (waves * 64) / 256;        // 8192
    sparse_codebook_w<<<blocks, 256, 0, stream>>>(codes, pred, tab, out);
}